// Round 1
// baseline (884.088 us; speedup 1.0000x reference)
//
#include <hip/hip_runtime.h>
#include <stdint.h>

#define NB      22743     // total boxes per batch (3*(19^2+38^2+76^2))
#define L0N     1083      // level0 box count (3*361)
#define L1N     5415      // level0+level1 (3*361+3*1444)
#define PRE     400
#define TOPK_N  200
#define CAP     2048
#define NBATCH  8
#define NBINS   4096

typedef unsigned long long u64;
typedef unsigned int u32;

__device__ __forceinline__ float sigf(float x) { return 1.0f / (1.0f + expf(-x)); }

// order-preserving f32 -> u32 mapping
__device__ __forceinline__ u32 mono32(float f) {
    u32 u = __float_as_uint(f);
    return (u & 0x80000000u) ? ~u : (u | 0x80000000u);
}
__device__ __forceinline__ float unmono(u32 m) {
    u32 u = (m & 0x80000000u) ? (m & 0x7FFFFFFFu) : ~m;
    return __uint_as_float(u);
}

// pointer to field-0 of box g in batch b, plus geometry
__device__ __forceinline__ const float* box_base(
    const float* f0, const float* f1, const float* f2,
    int b, int g, int* HW, int* cw, int* ch, float* stride, float* aw, float* ah)
{
    const float* f; int W, off, li;
    if (g < L0N)      { f = f0; W = 19; off = 0;   li = 0; *stride = 32.f; }
    else if (g < L1N) { f = f1; W = 38; off = L0N; li = 1; *stride = 16.f; }
    else              { f = f2; W = 76; off = L1N; li = 2; *stride = 8.f;  }
    const float AWt[3][3] = {{116.f,156.f,373.f},{30.f,62.f,59.f},{10.f,16.f,33.f}};
    const float AHt[3][3] = {{90.f,198.f,326.f},{61.f,45.f,119.f},{13.f,30.f,23.f}};
    int hw = W * W;
    int local = g - off;
    int a = local / hw; int r = local - a * hw;
    int h = r / W; int w = r - h * W;
    *HW = hw; *cw = w; *ch = h;
    *aw = AWt[li][a]; *ah = AHt[li][a];
    return f + (size_t)((b * 255 + a * 85) * hw + h * W + w);
}

// MODE 0: histogram of top-12 bits of mono.
// MODE 1: histogram of bits [19:8] for elements whose top-12 == sel1[b].x.
// MODE 2: gather candidates with (mono>>8) >= t24[b].
template<int MODE>
__global__ void score_pass(const float* __restrict__ f0, const float* __restrict__ f1,
                           const float* __restrict__ f2,
                           u32* __restrict__ ghist, const int2* __restrict__ sel1,
                           const int* __restrict__ t24, u32* __restrict__ cnt,
                           u64* __restrict__ cand)
{
    __shared__ u32 h[NBINS];
    const int b = blockIdx.y;
    if (MODE == 0 || MODE == 1) {
        for (int i = threadIdx.x; i < NBINS; i += blockDim.x) h[i] = 0;
        __syncthreads();
    }
    const int g = blockIdx.x * blockDim.x + threadIdx.x;
    if (g < NB) {
        int HW, cw, ch; float stride, aw, ah;
        const float* p = box_base(f0, f1, f2, b, g, &HW, &cw, &ch, &stride, &aw, &ah);
        float conf = sigf(p[4 * HW]);
        u32 b1 = 0, T = 0;
        if (MODE == 1) b1 = (u32)sel1[b].x;
        if (MODE == 2) T = (u32)t24[b];
        for (int c = 0; c < 80; ++c) {
            float s = conf * sigf(p[(5 + c) * HW]);
            s = (s >= 0.01f) ? s : -1.0f;   // matches reference threshold replace
            u32 m = mono32(s);
            if (MODE == 0) {
                atomicAdd(&h[m >> 20], 1u);
            } else if (MODE == 1) {
                if ((m >> 20) == b1) atomicAdd(&h[(m >> 8) & 0xFFFu], 1u);
            } else {
                if ((m >> 8) >= T) {
                    u32 pos = atomicAdd(&cnt[b], 1u);
                    if (pos < CAP) {
                        u32 e = (u32)(g * 80 + c);   // reference flat index
                        cand[b * CAP + pos] = ((u64)m << 32) | (u64)(0xFFFFFFFFu - e);
                    }
                }
            }
        }
    }
    if (MODE == 0 || MODE == 1) {
        __syncthreads();
        u32* gh = ghist + b * NBINS;
        for (int i = threadIdx.x; i < NBINS; i += blockDim.x)
            if (h[i]) atomicAdd(&gh[i], h[i]);
    }
}

__global__ void scan1_k(const u32* __restrict__ ghist1, int2* __restrict__ sel1)
{
    int b = threadIdx.x;
    if (b >= NBATCH) return;
    const u32* h = ghist1 + b * NBINS;
    u32 cum = 0;
    for (int bin = NBINS - 1; bin >= 0; --bin) {
        u32 c = h[bin];
        if (cum + c >= PRE) { sel1[b] = make_int2(bin, (int)cum); return; }
        cum += c;
    }
    sel1[b] = make_int2(0, 0);
}

__global__ void scan2_k(const u32* __restrict__ ghist2, const int2* __restrict__ sel1,
                        int* __restrict__ t24)
{
    int b = threadIdx.x;
    if (b >= NBATCH) return;
    u32 need = (u32)(PRE - sel1[b].y);   // sel1[b].y < 400 always
    const u32* h = ghist2 + b * NBINS;
    u32 cum = 0;
    for (int bin = NBINS - 1; bin >= 0; --bin) {
        u32 c = h[bin];
        if (cum + c >= need) { t24[b] = (sel1[b].x << 12) | bin; return; }
        cum += c;
    }
    t24[b] = (sel1[b].x << 12);
}

__global__ __launch_bounds__(256) void final_k(
    const float* __restrict__ f0, const float* __restrict__ f1, const float* __restrict__ f2,
    const u32* __restrict__ cnt, const u64* __restrict__ cand, float* __restrict__ out)
{
    __shared__ u64 keys[CAP];
    __shared__ float X1[PRE], Y1[PRE], X2[PRE], Y2[PRE], VAL[PRE];
    __shared__ int CLS[PRE];
    __shared__ int KV[PRE];        // keep && valid
    __shared__ int SEL[TOPK_N];
    __shared__ int PAD[TOPK_N];

    const int b = blockIdx.x;
    const int tid = threadIdx.x;
    const u32 n = min(cnt[b], (u32)CAP);

    for (int i = tid; i < CAP; i += 256)
        keys[i] = (i < (int)n) ? cand[b * CAP + i] : 0ull;
    __syncthreads();

    // bitonic sort descending (keys unique except pad zeros, which sort last)
    for (int k = 2; k <= CAP; k <<= 1) {
        for (int j = k >> 1; j > 0; j >>= 1) {
            for (int i = tid; i < CAP; i += 256) {
                int l = i ^ j;
                if (l > i) {
                    u64 a = keys[i], c = keys[l];
                    bool desc = ((i & k) == 0);
                    if (desc ? (a < c) : (a > c)) { keys[i] = c; keys[l] = a; }
                }
            }
            __syncthreads();
        }
    }

    // top-400: recover value/index, decode boxes to corners
    for (int i = tid; i < PRE; i += 256) {
        u64 kk = keys[i];
        float v; int g, c;
        if (kk == 0ull) { v = -1.0f; g = 0; c = 0; }
        else {
            u32 m = (u32)(kk >> 32);
            u32 e = 0xFFFFFFFFu - (u32)(kk & 0xFFFFFFFFu);
            v = unmono(m);
            g = (int)(e / 80u);
            c = (int)(e - (u32)g * 80u);
        }
        VAL[i] = v; CLS[i] = c; KV[i] = (v >= 0.01f) ? 1 : 0;
        int HW, cw, ch; float stride, aw, ah;
        const float* p = box_base(f0, f1, f2, b, g, &HW, &cw, &ch, &stride, &aw, &ah);
        float cx = (sigf(p[0])      + (float)cw) * stride;
        float cy = (sigf(p[HW])     + (float)ch) * stride;
        float bw = expf(p[2 * HW]) * aw;
        float bh = expf(p[3 * HW]) * ah;
        X1[i] = cx - bw * 0.5f; Y1[i] = cy - bh * 0.5f;
        X2[i] = cx + bw * 0.5f; Y2[i] = cy + bh * 0.5f;
    }
    __syncthreads();

    // greedy NMS, exact reference semantics
    for (int i = 0; i < PRE - 1; ++i) {
        if (KV[i]) {               // uniform branch (same LDS value for all threads)
            float x1i = X1[i], y1i = Y1[i], x2i = X2[i], y2i = Y2[i];
            int ci = CLS[i];
            float ai = fmaxf(x2i - x1i, 0.f) * fmaxf(y2i - y1i, 0.f);
            for (int j = i + 1 + tid; j < PRE; j += 256) {
                if (CLS[j] == ci) {
                    float ix1 = fmaxf(x1i, X1[j]);
                    float iy1 = fmaxf(y1i, Y1[j]);
                    float ix2 = fminf(x2i, X2[j]);
                    float iy2 = fminf(y2i, Y2[j]);
                    float inter = fmaxf(ix2 - ix1, 0.f) * fmaxf(iy2 - iy1, 0.f);
                    float aj = fmaxf(X2[j] - X1[j], 0.f) * fmaxf(Y2[j] - Y1[j], 0.f);
                    float iou = inter / fmaxf(ai + aj - inter, 1e-9f);
                    if (iou > 0.45f) KV[j] = 0;
                }
            }
        }
        __syncthreads();
    }

    // top-200 of (kept ? val : -1): kept positions in order, then pads in order
    if (tid == 0) {
        int o = 0;
        for (int j = 0; j < PRE && o < TOPK_N; ++j)
            if (KV[j]) { SEL[o] = j; PAD[o] = 0; ++o; }
        for (int j = 0; j < PRE && o < TOPK_N; ++j)
            if (!KV[j]) { SEL[o] = j; PAD[o] = 1; ++o; }
    }
    __syncthreads();

    for (int k = tid; k < TOPK_N; k += 256) {
        float* o = out + ((size_t)b * TOPK_N + k) * 6;
        if (PAD[k]) {
            o[0] = 0.f; o[1] = 0.f; o[2] = 0.f; o[3] = 0.f; o[4] = 0.f; o[5] = -1.f;
        } else {
            int j = SEL[k];
            o[0] = X1[j]; o[1] = Y1[j]; o[2] = X2[j]; o[3] = Y2[j];
            o[4] = VAL[j]; o[5] = (float)CLS[j];
        }
    }
}

extern "C" void kernel_launch(void* const* d_in, const int* in_sizes, int n_in,
                              void* d_out, int out_size, void* d_ws, size_t ws_size,
                              hipStream_t stream)
{
    const float* f0 = (const float*)d_in[0];
    const float* f1 = (const float*)d_in[1];
    const float* f2 = (const float*)d_in[2];
    float* out = (float*)d_out;
    char* ws = (char*)d_ws;

    // ws layout (fixed offsets, ~393 KB total)
    u32*  ghist1 = (u32*)(ws);              // 8*4096*4 = 131072
    u32*  ghist2 = (u32*)(ws + 131072);     // 131072
    u32*  cnt    = (u32*)(ws + 262144);     // 32
    int2* sel1   = (int2*)(ws + 262176);    // 64
    int*  t24    = (int*)(ws + 262240);     // 32
    u64*  cand   = (u64*)(ws + 262272);     // 8*2048*8 = 131072

    hipMemsetAsync(ws, 0, 262176, stream);  // zero ghist1, ghist2, cnt

    dim3 grid((NB + 255) / 256, NBATCH);
    score_pass<0><<<grid, 256, 0, stream>>>(f0, f1, f2, ghist1, sel1, t24, cnt, cand);
    scan1_k<<<1, 64, 0, stream>>>(ghist1, sel1);
    score_pass<1><<<grid, 256, 0, stream>>>(f0, f1, f2, ghist2, sel1, t24, cnt, cand);
    scan2_k<<<1, 64, 0, stream>>>(ghist2, sel1, t24);
    score_pass<2><<<grid, 256, 0, stream>>>(f0, f1, f2, ghist1, sel1, t24, cnt, cand);
    final_k<<<NBATCH, 256, 0, stream>>>(f0, f1, f2, cnt, cand, out);
}

// Round 2
// 475.556 us; speedup vs baseline: 1.8591x; 1.8591x over previous
//
#include <hip/hip_runtime.h>
#include <stdint.h>

#define NB      22743     // total boxes per batch (3*(19^2+38^2+76^2))
#define L0N     1083      // level0 box count (3*361)
#define L1N     5415      // level0+level1 (3*361+3*1444)
#define PRE     400
#define TOPK_N  200
#define CAP     2048
#define NBATCH  8
#define NBINS   4096
#define MIN_VALID_PFX  ((int)(0xBC23D70Au >> 8))   // mono(0.01f) >> 8

typedef unsigned long long u64;
typedef unsigned int u32;

__device__ __forceinline__ float sigf(float x) { return 1.0f / (1.0f + expf(-x)); }

// order-preserving f32 -> u32 mapping
__device__ __forceinline__ u32 mono32(float f) {
    u32 u = __float_as_uint(f);
    return (u & 0x80000000u) ? ~u : (u | 0x80000000u);
}
__device__ __forceinline__ float unmono(u32 m) {
    u32 u = (m & 0x80000000u) ? (m & 0x7FFFFFFFu) : ~m;
    return __uint_as_float(u);
}

// pointer to field-0 of box g in batch b, plus geometry
__device__ __forceinline__ const float* box_base(
    const float* f0, const float* f1, const float* f2,
    int b, int g, int* HW, int* cw, int* ch, float* stride, float* aw, float* ah)
{
    const float* f; int W, off, li;
    if (g < L0N)      { f = f0; W = 19; off = 0;   li = 0; *stride = 32.f; }
    else if (g < L1N) { f = f1; W = 38; off = L0N; li = 1; *stride = 16.f; }
    else              { f = f2; W = 76; off = L1N; li = 2; *stride = 8.f;  }
    const float AWt[3][3] = {{116.f,156.f,373.f},{30.f,62.f,59.f},{10.f,16.f,33.f}};
    const float AHt[3][3] = {{90.f,198.f,326.f},{61.f,45.f,119.f},{13.f,30.f,23.f}};
    int hw = W * W;
    int local = g - off;
    int a = local / hw; int r = local - a * hw;
    int h = r / W; int w = r - h * W;
    *HW = hw; *cw = w; *ch = h;
    *aw = AWt[li][a]; *ah = AHt[li][a];
    return f + (size_t)((b * 255 + a * 85) * hw + h * W + w);
}

// MODE 0: histogram of top-12 bits of mono (valid scores only).
// MODE 1: histogram of bits [19:8] for valid elements whose top-12 == sel1[b].x.
// MODE 2: gather candidates with (mono>>8) >= t24[b].
template<int MODE>
__global__ void score_pass(const float* __restrict__ f0, const float* __restrict__ f1,
                           const float* __restrict__ f2,
                           u32* __restrict__ ghist, const int2* __restrict__ sel1,
                           const int* __restrict__ t24, u32* __restrict__ cnt,
                           u64* __restrict__ cand)
{
    __shared__ u32 h[NBINS];
    const int b = blockIdx.y;
    if (MODE == 0 || MODE == 1) {
        for (int i = threadIdx.x; i < NBINS; i += blockDim.x) h[i] = 0;
        __syncthreads();
    }
    const int g = blockIdx.x * blockDim.x + threadIdx.x;
    if (g < NB) {
        int HW, cw, ch; float stride, aw, ah;
        const float* p = box_base(f0, f1, f2, b, g, &HW, &cw, &ch, &stride, &aw, &ah);
        float conf = sigf(p[4 * HW]);
        u32 b1 = 0, T = 0;
        if (MODE == 1) b1 = (u32)sel1[b].x;
        if (MODE == 2) T = (u32)t24[b];
        for (int c = 0; c < 80; ++c) {
            float s = conf * sigf(p[(5 + c) * HW]);
            // sub-threshold scores become exactly -1.0 in the reference; any -1
            // row in the final top-200 emits (0,0,0,0,0,-1) and is inert in NMS,
            // so -1 entries are interchangeable with pad entries -> skip them.
            if (s < 0.01f) continue;
            u32 m = mono32(s);
            if (MODE == 0) {
                atomicAdd(&h[m >> 20], 1u);
            } else if (MODE == 1) {
                if ((m >> 20) == b1) atomicAdd(&h[(m >> 8) & 0xFFFu], 1u);
            } else {
                if ((m >> 8) >= T) {
                    u32 pos = atomicAdd(&cnt[b], 1u);
                    if (pos < CAP) {
                        u32 e = (u32)(g * 80 + c);   // reference flat index
                        cand[b * CAP + pos] = ((u64)m << 32) | (u64)(0xFFFFFFFFu - e);
                    }
                }
            }
        }
    }
    if (MODE == 0 || MODE == 1) {
        __syncthreads();
        u32* gh = ghist + b * NBINS;
        for (int i = threadIdx.x; i < NBINS; i += blockDim.x)
            if (h[i]) atomicAdd(&gh[i], h[i]);
    }
}

// Parallel pivot search. LEVEL 1: find top-12-bit pivot bin p with
// suffix_count(p+1) < PRE <= suffix_count(p); write sel1=(p, suffix_count(p+1)).
// LEVEL 2: same over bits [19:8] with need = PRE - sel1.y; write clamped t24.
template<int LEVEL>
__global__ __launch_bounds__(256) void scan_k(const u32* __restrict__ ghist,
                                              int2* __restrict__ sel1,
                                              int* __restrict__ t24)
{
    const int b = blockIdx.x;
    const int tid = threadIdx.x;
    const u32* h = ghist + b * NBINS;
    __shared__ u32 lh[NBINS];
    __shared__ u32 part[256];
    __shared__ u32 suf[256];

    const u32 need = (LEVEL == 1) ? (u32)PRE : (u32)(PRE - sel1[b].y);

    for (int i = tid; i < NBINS; i += 256) lh[i] = h[i];
    // defaults (overwritten by the crossing thread after the syncs below)
    if (tid == 0) {
        if (LEVEL == 1) sel1[b] = make_int2(0, 0);
        else            t24[b]  = MIN_VALID_PFX;    // degenerate: gather all valid
    }
    __syncthreads();

    u32 ps = 0;
    #pragma unroll
    for (int i = 0; i < 16; ++i) ps += lh[tid * 16 + i];
    part[tid] = ps;
    __syncthreads();

    if (tid == 0) {
        u32 cum = 0;
        for (int t = 255; t >= 0; --t) { suf[t] = cum; cum += part[t]; }
    }
    __syncthreads();

    // exactly one chunk crosses `need` (if total >= need)
    if (suf[tid] < need && suf[tid] + part[tid] >= need) {
        u32 cum = suf[tid];
        for (int bin = tid * 16 + 15; bin >= tid * 16; --bin) {
            u32 c = lh[bin];
            if (cum + c >= need) {
                if (LEVEL == 1) {
                    sel1[b] = make_int2(bin, (int)cum);
                } else {
                    int t = (sel1[b].x << 12) | bin;
                    t24[b] = (t > MIN_VALID_PFX) ? t : MIN_VALID_PFX;
                }
                break;
            }
            cum += c;
        }
    }
}

__global__ __launch_bounds__(256) void final_k(
    const float* __restrict__ f0, const float* __restrict__ f1, const float* __restrict__ f2,
    const u32* __restrict__ cnt, const u64* __restrict__ cand, float* __restrict__ out)
{
    __shared__ u64 keys[CAP];
    __shared__ float X1[PRE], Y1[PRE], X2[PRE], Y2[PRE], VAL[PRE];
    __shared__ int CLS[PRE];
    __shared__ int KV[PRE];        // keep && valid
    __shared__ int SEL[TOPK_N];
    __shared__ int PAD[TOPK_N];

    const int b = blockIdx.x;
    const int tid = threadIdx.x;
    const u32 n = min(cnt[b], (u32)CAP);

    for (int i = tid; i < CAP; i += 256)
        keys[i] = (i < (int)n) ? cand[b * CAP + i] : 0ull;
    __syncthreads();

    // bitonic sort descending (keys unique except pad zeros, which sort last)
    for (int k = 2; k <= CAP; k <<= 1) {
        for (int j = k >> 1; j > 0; j >>= 1) {
            for (int i = tid; i < CAP; i += 256) {
                int l = i ^ j;
                if (l > i) {
                    u64 a = keys[i], c = keys[l];
                    bool desc = ((i & k) == 0);
                    if (desc ? (a < c) : (a > c)) { keys[i] = c; keys[l] = a; }
                }
            }
            __syncthreads();
        }
    }

    // top-400: recover value/index, decode boxes to corners
    for (int i = tid; i < PRE; i += 256) {
        u64 kk = keys[i];
        float v; int g, c;
        if (kk == 0ull) { v = -1.0f; g = 0; c = 0; }
        else {
            u32 m = (u32)(kk >> 32);
            u32 e = 0xFFFFFFFFu - (u32)(kk & 0xFFFFFFFFu);
            v = unmono(m);
            g = (int)(e / 80u);
            c = (int)(e - (u32)g * 80u);
        }
        VAL[i] = v; CLS[i] = c; KV[i] = (v >= 0.01f) ? 1 : 0;
        int HW, cw, ch; float stride, aw, ah;
        const float* p = box_base(f0, f1, f2, b, g, &HW, &cw, &ch, &stride, &aw, &ah);
        float cx = (sigf(p[0])      + (float)cw) * stride;
        float cy = (sigf(p[HW])     + (float)ch) * stride;
        float bw = expf(p[2 * HW]) * aw;
        float bh = expf(p[3 * HW]) * ah;
        X1[i] = cx - bw * 0.5f; Y1[i] = cy - bh * 0.5f;
        X2[i] = cx + bw * 0.5f; Y2[i] = cy + bh * 0.5f;
    }
    __syncthreads();

    // greedy NMS, exact reference semantics
    for (int i = 0; i < PRE - 1; ++i) {
        if (KV[i]) {               // uniform branch (same LDS value for all threads)
            float x1i = X1[i], y1i = Y1[i], x2i = X2[i], y2i = Y2[i];
            int ci = CLS[i];
            float ai = fmaxf(x2i - x1i, 0.f) * fmaxf(y2i - y1i, 0.f);
            for (int j = i + 1 + tid; j < PRE; j += 256) {
                if (CLS[j] == ci) {
                    float ix1 = fmaxf(x1i, X1[j]);
                    float iy1 = fmaxf(y1i, Y1[j]);
                    float ix2 = fminf(x2i, X2[j]);
                    float iy2 = fminf(y2i, Y2[j]);
                    float inter = fmaxf(ix2 - ix1, 0.f) * fmaxf(iy2 - iy1, 0.f);
                    float aj = fmaxf(X2[j] - X1[j], 0.f) * fmaxf(Y2[j] - Y1[j], 0.f);
                    float iou = inter / fmaxf(ai + aj - inter, 1e-9f);
                    if (iou > 0.45f) KV[j] = 0;
                }
            }
        }
        __syncthreads();
    }

    // top-200 of (kept ? val : -1): kept positions in order, then pads in order
    if (tid == 0) {
        int o = 0;
        for (int j = 0; j < PRE && o < TOPK_N; ++j)
            if (KV[j]) { SEL[o] = j; PAD[o] = 0; ++o; }
        for (int j = 0; j < PRE && o < TOPK_N; ++j)
            if (!KV[j]) { SEL[o] = j; PAD[o] = 1; ++o; }
    }
    __syncthreads();

    for (int k = tid; k < TOPK_N; k += 256) {
        float* o = out + ((size_t)b * TOPK_N + k) * 6;
        if (PAD[k]) {
            o[0] = 0.f; o[1] = 0.f; o[2] = 0.f; o[3] = 0.f; o[4] = 0.f; o[5] = -1.f;
        } else {
            int j = SEL[k];
            o[0] = X1[j]; o[1] = Y1[j]; o[2] = X2[j]; o[3] = Y2[j];
            o[4] = VAL[j]; o[5] = (float)CLS[j];
        }
    }
}

extern "C" void kernel_launch(void* const* d_in, const int* in_sizes, int n_in,
                              void* d_out, int out_size, void* d_ws, size_t ws_size,
                              hipStream_t stream)
{
    const float* f0 = (const float*)d_in[0];
    const float* f1 = (const float*)d_in[1];
    const float* f2 = (const float*)d_in[2];
    float* out = (float*)d_out;
    char* ws = (char*)d_ws;

    // ws layout (fixed offsets, ~393 KB total)
    u32*  ghist1 = (u32*)(ws);              // 8*4096*4 = 131072
    u32*  ghist2 = (u32*)(ws + 131072);     // 131072
    u32*  cnt    = (u32*)(ws + 262144);     // 32
    int2* sel1   = (int2*)(ws + 262176);    // 64
    int*  t24    = (int*)(ws + 262240);     // 32
    u64*  cand   = (u64*)(ws + 262272);     // 8*2048*8 = 131072

    hipMemsetAsync(ws, 0, 262176, stream);  // zero ghist1, ghist2, cnt

    dim3 grid((NB + 255) / 256, NBATCH);
    score_pass<0><<<grid, 256, 0, stream>>>(f0, f1, f2, ghist1, sel1, t24, cnt, cand);
    scan_k<1><<<NBATCH, 256, 0, stream>>>(ghist1, sel1, t24);
    score_pass<1><<<grid, 256, 0, stream>>>(f0, f1, f2, ghist2, sel1, t24, cnt, cand);
    scan_k<2><<<NBATCH, 256, 0, stream>>>(ghist2, sel1, t24);
    score_pass<2><<<grid, 256, 0, stream>>>(f0, f1, f2, ghist1, sel1, t24, cnt, cand);
    final_k<<<NBATCH, 256, 0, stream>>>(f0, f1, f2, cnt, cand, out);
}

// Round 3
// 378.735 us; speedup vs baseline: 2.3343x; 1.2556x over previous
//
#include <hip/hip_runtime.h>
#include <stdint.h>

#define NB      22743     // total boxes per batch (3*(19^2+38^2+76^2))
#define L0N     1083      // level0 box count (3*361)
#define L1N     5415      // level0+level1 (3*361+3*1444)
#define PRE     400
#define TOPK_N  200
#define CAP     2048
#define NBATCH  8
#define NBINS   4096
#define MIN_VALID_PFX  ((int)(0xBC23D70Au >> 8))   // mono(0.01f) >> 8

typedef unsigned long long u64;
typedef unsigned int u32;

__device__ __forceinline__ float sigf(float x) { return 1.0f / (1.0f + expf(-x)); }

// order-preserving f32 -> u32 mapping
__device__ __forceinline__ u32 mono32(float f) {
    u32 u = __float_as_uint(f);
    return (u & 0x80000000u) ? ~u : (u | 0x80000000u);
}
__device__ __forceinline__ float unmono(u32 m) {
    u32 u = (m & 0x80000000u) ? (m & 0x7FFFFFFFu) : ~m;
    return __uint_as_float(u);
}

// pointer to field-0 of box g in batch b, plus geometry
__device__ __forceinline__ const float* box_base(
    const float* f0, const float* f1, const float* f2,
    int b, int g, int* HW, int* cw, int* ch, float* stride, float* aw, float* ah)
{
    const float* f; int W, off, li;
    if (g < L0N)      { f = f0; W = 19; off = 0;   li = 0; *stride = 32.f; }
    else if (g < L1N) { f = f1; W = 38; off = L0N; li = 1; *stride = 16.f; }
    else              { f = f2; W = 76; off = L1N; li = 2; *stride = 8.f;  }
    const float AWt[3][3] = {{116.f,156.f,373.f},{30.f,62.f,59.f},{10.f,16.f,33.f}};
    const float AHt[3][3] = {{90.f,198.f,326.f},{61.f,45.f,119.f},{13.f,30.f,23.f}};
    int hw = W * W;
    int local = g - off;
    int a = local / hw; int r = local - a * hw;
    int h = r / W; int w = r - h * W;
    *HW = hw; *cw = w; *ch = h;
    *aw = AWt[li][a]; *ah = AHt[li][a];
    return f + (size_t)((b * 255 + a * 85) * hw + h * W + w);
}

// MODE 0: histogram of top-12 bits of mono (valid scores only).
// MODE 1: histogram of bits [19:8] for valid elements whose top-12 == sel1[b].x.
// MODE 2: gather candidates with (mono>>8) >= t24[b].
template<int MODE>
__global__ void score_pass(const float* __restrict__ f0, const float* __restrict__ f1,
                           const float* __restrict__ f2,
                           u32* __restrict__ ghist, const int2* __restrict__ sel1,
                           const int* __restrict__ t24, u32* __restrict__ cnt,
                           u64* __restrict__ cand)
{
    __shared__ u32 h[NBINS];
    const int b = blockIdx.y;
    if (MODE == 0 || MODE == 1) {
        for (int i = threadIdx.x; i < NBINS; i += blockDim.x) h[i] = 0;
        __syncthreads();
    }
    const int g = blockIdx.x * blockDim.x + threadIdx.x;
    if (g < NB) {
        int HW, cw, ch; float stride, aw, ah;
        const float* p = box_base(f0, f1, f2, b, g, &HW, &cw, &ch, &stride, &aw, &ah);
        float conf = sigf(p[4 * HW]);
        u32 b1 = 0, T = 0;
        if (MODE == 1) b1 = (u32)sel1[b].x;
        if (MODE == 2) T = (u32)t24[b];
        for (int c = 0; c < 80; ++c) {
            float s = conf * sigf(p[(5 + c) * HW]);
            // sub-threshold scores become exactly -1.0 in the reference; any -1
            // row in the final top-200 emits (0,0,0,0,0,-1) and is inert in NMS,
            // so -1 entries are interchangeable with pad entries -> skip them.
            if (s < 0.01f) continue;
            u32 m = mono32(s);
            if (MODE == 0) {
                atomicAdd(&h[m >> 20], 1u);
            } else if (MODE == 1) {
                if ((m >> 20) == b1) atomicAdd(&h[(m >> 8) & 0xFFFu], 1u);
            } else {
                if ((m >> 8) >= T) {
                    u32 pos = atomicAdd(&cnt[b], 1u);
                    if (pos < CAP) {
                        u32 e = (u32)(g * 80 + c);   // reference flat index
                        cand[b * CAP + pos] = ((u64)m << 32) | (u64)(0xFFFFFFFFu - e);
                    }
                }
            }
        }
    }
    if (MODE == 0 || MODE == 1) {
        __syncthreads();
        u32* gh = ghist + b * NBINS;
        for (int i = threadIdx.x; i < NBINS; i += blockDim.x)
            if (h[i]) atomicAdd(&gh[i], h[i]);
    }
}

// Parallel pivot search. LEVEL 1: find top-12-bit pivot bin p with
// suffix_count(p+1) < PRE <= suffix_count(p); write sel1=(p, suffix_count(p+1)).
// LEVEL 2: same over bits [19:8] with need = PRE - sel1.y; write clamped t24.
template<int LEVEL>
__global__ __launch_bounds__(256) void scan_k(const u32* __restrict__ ghist,
                                              int2* __restrict__ sel1,
                                              int* __restrict__ t24)
{
    const int b = blockIdx.x;
    const int tid = threadIdx.x;
    const u32* h = ghist + b * NBINS;
    __shared__ u32 lh[NBINS];
    __shared__ u32 part[256];
    __shared__ u32 suf[256];

    const u32 need = (LEVEL == 1) ? (u32)PRE : (u32)(PRE - sel1[b].y);

    for (int i = tid; i < NBINS; i += 256) lh[i] = h[i];
    // defaults (overwritten by the crossing thread after the syncs below)
    if (tid == 0) {
        if (LEVEL == 1) sel1[b] = make_int2(0, 0);
        else            t24[b]  = MIN_VALID_PFX;    // degenerate: gather all valid
    }
    __syncthreads();

    u32 ps = 0;
    #pragma unroll
    for (int i = 0; i < 16; ++i) ps += lh[tid * 16 + i];
    part[tid] = ps;
    __syncthreads();

    if (tid == 0) {
        u32 cum = 0;
        for (int t = 255; t >= 0; --t) { suf[t] = cum; cum += part[t]; }
    }
    __syncthreads();

    // exactly one chunk crosses `need` (if total >= need)
    if (suf[tid] < need && suf[tid] + part[tid] >= need) {
        u32 cum = suf[tid];
        for (int bin = tid * 16 + 15; bin >= tid * 16; --bin) {
            u32 c = lh[bin];
            if (cum + c >= need) {
                if (LEVEL == 1) {
                    sel1[b] = make_int2(bin, (int)cum);
                } else {
                    int t = (sel1[b].x << 12) | bin;
                    t24[b] = (t > MIN_VALID_PFX) ? t : MIN_VALID_PFX;
                }
                break;
            }
            cum += c;
        }
    }
}

// Final stage: rank-sort candidates, decode top-400 boxes, bitmask NMS,
// rank-select top-200 and write output. 5 barriers total.
__global__ __launch_bounds__(256) void final_k(
    const float* __restrict__ f0, const float* __restrict__ f1, const float* __restrict__ f2,
    const u32* __restrict__ cnt, const u64* __restrict__ cand, float* __restrict__ out)
{
    __shared__ u64 keys[CAP];
    __shared__ u64 SKEY[PRE];                 // rank-sorted keys (0 = pad)
    __shared__ float X1[PRE], Y1[PRE], X2[PRE], Y2[PRE], VAL[PRE];
    __shared__ int CLS[PRE];
    __shared__ u64 SUP[PRE][8];               // suppression bitmask rows (word 7 = 0)
    __shared__ u64 VBM[8];                    // valid bitmask
    __shared__ u64 KBM[8];                    // final keep bitmask

    const int b = blockIdx.x;
    const int tid = threadIdx.x;
    const int n = (int)min(cnt[b], (u32)CAP);

    // ---- stage candidates + init SKEY ----
    for (int i = tid; i < n; i += 256) keys[i] = cand[b * CAP + i];
    for (int i = tid; i < PRE; i += 256) SKEY[i] = 0ull;
    if (tid < 8) { VBM[tid] = 0ull; KBM[tid] = 0ull; }
    __syncthreads();

    // ---- rank sort (keys unique; descending = (val desc, idx asc)) ----
    // inner loop reads the same LDS word across all lanes -> broadcast.
    for (int e = tid; e < n; e += 256) {
        u64 my = keys[e];
        int r = 0;
        for (int k = 0; k < n; ++k) r += (keys[k] > my);
        if (r < PRE) SKEY[r] = my;
    }
    __syncthreads();

    // ---- decode top-400 to corner boxes + valid ballot ----
    #pragma unroll
    for (int rr = 0; rr < 2; ++rr) {
        int i = rr * 256 + tid;
        bool valid = false;
        if (i < PRE) {
            u64 kk = SKEY[i];
            float v; int g, c;
            if (kk == 0ull) { v = -1.0f; g = 0; c = 0; }
            else {
                u32 m = (u32)(kk >> 32);
                u32 e = 0xFFFFFFFFu - (u32)(kk & 0xFFFFFFFFu);
                v = unmono(m);
                g = (int)(e / 80u);
                c = (int)(e - (u32)g * 80u);
                valid = true;                 // gathered scores are all >= 0.01
            }
            VAL[i] = v; CLS[i] = c;
            int HW, cw, ch; float stride, aw, ah;
            const float* p = box_base(f0, f1, f2, b, g, &HW, &cw, &ch, &stride, &aw, &ah);
            float cx = (sigf(p[0])      + (float)cw) * stride;
            float cy = (sigf(p[HW])     + (float)ch) * stride;
            float bw = expf(p[2 * HW]) * aw;
            float bh = expf(p[3 * HW]) * ah;
            X1[i] = cx - bw * 0.5f; Y1[i] = cy - bh * 0.5f;
            X2[i] = cx + bw * 0.5f; Y2[i] = cy + bh * 0.5f;
        }
        u64 bal = __ballot(valid);
        if ((tid & 63) == 0) VBM[rr * 4 + (tid >> 6)] = bal;
    }
    __syncthreads();

    // ---- suppression matrix: SUP[i][w] bit (j-64w) = i suppresses j (j>i) ----
    for (int t = tid; t < PRE * 8; t += 256) {
        int i = t >> 3, w = t & 7;
        u64 mask = 0ull;
        if (w >= (i >> 6)) {
            float x1i = X1[i], y1i = Y1[i], x2i = X2[i], y2i = Y2[i];
            int ci = CLS[i];
            float ai = fmaxf(x2i - x1i, 0.f) * fmaxf(y2i - y1i, 0.f);
            int jbase = w << 6;
            int j0 = (jbase > i + 1) ? jbase : (i + 1);
            int j1 = (jbase + 64 < PRE) ? (jbase + 64) : PRE;
            for (int j = j0; j < j1; ++j) {
                if (CLS[j] == ci) {
                    float ix1 = fmaxf(x1i, X1[j]);
                    float iy1 = fmaxf(y1i, Y1[j]);
                    float ix2 = fminf(x2i, X2[j]);
                    float iy2 = fminf(y2i, Y2[j]);
                    float inter = fmaxf(ix2 - ix1, 0.f) * fmaxf(iy2 - iy1, 0.f);
                    float aj = fmaxf(X2[j] - X1[j], 0.f) * fmaxf(Y2[j] - Y1[j], 0.f);
                    float iou = inter / fmaxf(ai + aj - inter, 1e-9f);
                    if (iou > 0.45f) mask |= 1ull << (j - jbase);
                }
            }
        }
        SUP[i][w] = mask;
    }
    __syncthreads();

    // ---- greedy NMS over bitmasks (single thread, registers only, 2-deep
    //      A/B prefetch; all register indices compile-time per rule #20) ----
    if (tid == 0) {
        u64 kp[7], A[7], B[7];
        #pragma unroll
        for (int w = 0; w < 7; ++w) kp[w] = VBM[w];
        #pragma unroll
        for (int w = 0; w < 7; ++w) A[w] = SUP[0][w];
        #pragma unroll
        for (int w = 0; w < 7; ++w) B[w] = SUP[1][w];
        #pragma unroll
        for (int w = 0; w < 7; ++w) {
            const int base = w << 6;
            const int lim = (w == 6) ? 16 : 64;   // PRE = 400
            for (int bi = 0; bi < lim; bi += 2) {
                int i = base + bi;
                if ((kp[w] >> bi) & 1) {
                    #pragma unroll
                    for (int w2 = 0; w2 < 7; ++w2) kp[w2] &= ~A[w2];
                }
                int ip2 = (i + 2 < PRE) ? (i + 2) : (PRE - 1);
                #pragma unroll
                for (int w2 = 0; w2 < 7; ++w2) A[w2] = SUP[ip2][w2];
                if ((kp[w] >> (bi + 1)) & 1) {
                    #pragma unroll
                    for (int w2 = 0; w2 < 7; ++w2) kp[w2] &= ~B[w2];
                }
                int ip3 = (i + 3 < PRE) ? (i + 3) : (PRE - 1);
                #pragma unroll
                for (int w2 = 0; w2 < 7; ++w2) B[w2] = SUP[ip3][w2];
            }
        }
        #pragma unroll
        for (int w = 0; w < 7; ++w) KBM[w] = kp[w];
    }
    __syncthreads();

    // ---- rank-select top-200 and write output directly ----
    int totk = 0;
    #pragma unroll
    for (int w = 0; w < 7; ++w) totk += __popcll(KBM[w]);
    for (int j = tid; j < PRE; j += 256) {
        int w = j >> 6, bi = j & 63;
        int pre_kept = 0;
        for (int ww = 0; ww < w; ++ww) pre_kept += __popcll(KBM[ww]);
        u64 kw = KBM[w];
        pre_kept += __popcll(kw & ((1ull << bi) - 1ull));
        bool kept = (kw >> bi) & 1;
        int slot = kept ? pre_kept : (totk + j - pre_kept);
        if (slot < TOPK_N) {
            float* o = out + ((size_t)b * TOPK_N + slot) * 6;
            if (kept) {
                o[0] = X1[j]; o[1] = Y1[j]; o[2] = X2[j]; o[3] = Y2[j];
                o[4] = VAL[j]; o[5] = (float)CLS[j];
            } else {
                o[0] = 0.f; o[1] = 0.f; o[2] = 0.f; o[3] = 0.f; o[4] = 0.f; o[5] = -1.f;
            }
        }
    }
}

extern "C" void kernel_launch(void* const* d_in, const int* in_sizes, int n_in,
                              void* d_out, int out_size, void* d_ws, size_t ws_size,
                              hipStream_t stream)
{
    const float* f0 = (const float*)d_in[0];
    const float* f1 = (const float*)d_in[1];
    const float* f2 = (const float*)d_in[2];
    float* out = (float*)d_out;
    char* ws = (char*)d_ws;

    // ws layout (fixed offsets, ~393 KB total)
    u32*  ghist1 = (u32*)(ws);              // 8*4096*4 = 131072
    u32*  ghist2 = (u32*)(ws + 131072);     // 131072
    u32*  cnt    = (u32*)(ws + 262144);     // 32
    int2* sel1   = (int2*)(ws + 262176);    // 64
    int*  t24    = (int*)(ws + 262240);     // 32
    u64*  cand   = (u64*)(ws + 262272);     // 8*2048*8 = 131072

    hipMemsetAsync(ws, 0, 262176, stream);  // zero ghist1, ghist2, cnt

    dim3 grid((NB + 255) / 256, NBATCH);
    score_pass<0><<<grid, 256, 0, stream>>>(f0, f1, f2, ghist1, sel1, t24, cnt, cand);
    scan_k<1><<<NBATCH, 256, 0, stream>>>(ghist1, sel1, t24);
    score_pass<1><<<grid, 256, 0, stream>>>(f0, f1, f2, ghist2, sel1, t24, cnt, cand);
    scan_k<2><<<NBATCH, 256, 0, stream>>>(ghist2, sel1, t24);
    score_pass<2><<<grid, 256, 0, stream>>>(f0, f1, f2, ghist1, sel1, t24, cnt, cand);
    final_k<<<NBATCH, 256, 0, stream>>>(f0, f1, f2, cnt, cand, out);
}

// Round 6
// 312.279 us; speedup vs baseline: 2.8311x; 1.2128x over previous
//
#include <hip/hip_runtime.h>
#include <stdint.h>

#define NB      22743     // total boxes per batch (3*(19^2+38^2+76^2))
#define L0N     1083      // level0 box count (3*361)
#define L1N     5415      // level0+level1 (3*361+3*1444)
#define PRE     400
#define TOPK_N  200
#define CAP     2048
#define NBATCH  8
#define NBINS1  2048      // level-1: mono bits [31:21]
#define NBINS2  4096      // level-2: mono bits [20:9]
#define MIN_VALID_P9 (0xBC23D70Au >> 9)   // mono(0.01f) >> 9

typedef unsigned long long u64;
typedef unsigned int u32;

__device__ __forceinline__ float sigf(float x) { return 1.0f / (1.0f + expf(-x)); }

// order-preserving f32 -> u32 mapping
__device__ __forceinline__ u32 mono32(float f) {
    u32 u = __float_as_uint(f);
    return (u & 0x80000000u) ? ~u : (u | 0x80000000u);
}
__device__ __forceinline__ float unmono(u32 m) {
    u32 u = (m & 0x80000000u) ? (m & 0x7FFFFFFFu) : ~m;
    return __uint_as_float(u);
}

// pointer to field-0 of box g in batch b, plus geometry
__device__ __forceinline__ const float* box_base(
    const float* f0, const float* f1, const float* f2,
    int b, int g, int* HW, int* cw, int* ch, float* stride, float* aw, float* ah)
{
    const float* f; int W, off, li;
    if (g < L0N)      { f = f0; W = 19; off = 0;   li = 0; *stride = 32.f; }
    else if (g < L1N) { f = f1; W = 38; off = L0N; li = 1; *stride = 16.f; }
    else              { f = f2; W = 76; off = L1N; li = 2; *stride = 8.f;  }
    const float AWt[3][3] = {{116.f,156.f,373.f},{30.f,62.f,59.f},{10.f,16.f,33.f}};
    const float AHt[3][3] = {{90.f,198.f,326.f},{61.f,45.f,119.f},{13.f,30.f,23.f}};
    int hw = W * W;
    int local = g - off;
    int a = local / hw; int r = local - a * hw;
    int h = r / W; int w = r - h * W;
    *HW = hw; *cw = w; *ch = h;
    *aw = AWt[li][a]; *ah = AHt[li][a];
    return f + (size_t)((b * 255 + a * 85) * hw + h * W + w);
}

// MODE 0: level-1 histogram (bits[31:21], 2048 bins, x4 replicated vs hot-bin atomics).
// MODE 1: level-2 histogram (bits[20:9]) of elements whose level-1 bin == sel1[b].x.
// MODE 2: gather candidates with (mono>>9) >= t23[b].
// Passes 1/2 skip whole boxes when conf (an upper bound on every score, since
// score = conf*cls with cls<1) is already below the pivot/threshold prefix.
template<int MODE>
__global__ void score_pass(const float* __restrict__ f0, const float* __restrict__ f1,
                           const float* __restrict__ f2,
                           u32* __restrict__ ghist, const int2* __restrict__ sel1,
                           const u32* __restrict__ t23, u32* __restrict__ cnt,
                           u64* __restrict__ cand)
{
    __shared__ u32 h[(MODE == 0) ? NBINS1 * 4 : ((MODE == 1) ? NBINS2 : 1)];
    const int b = blockIdx.y;
    const int tid = threadIdx.x;
    if (MODE == 0) { for (int i = tid; i < NBINS1 * 4; i += 256) h[i] = 0; __syncthreads(); }
    if (MODE == 1) { for (int i = tid; i < NBINS2; i += 256) h[i] = 0; __syncthreads(); }

    const int g = blockIdx.x * blockDim.x + tid;
    if (g < NB) {
        int HW, cw, ch; float stride, aw, ah;
        const float* p = box_base(f0, f1, f2, b, g, &HW, &cw, &ch, &stride, &aw, &ah);
        float conf = sigf(p[4 * HW]);
        u32 b1 = 0, T = 0;
        if (MODE == 1) b1 = (u32)sel1[b].x;
        if (MODE == 2) T = t23[b];
        bool do_box;
        if (MODE == 0)      do_box = (conf >= 0.01f);            // conf<0.01 -> all scores invalid
        else if (MODE == 1) do_box = ((mono32(conf) >> 21) >= b1);
        else                do_box = ((mono32(conf) >> 9)  >= T);
        if (do_box) {
            for (int c = 0; c < 80; ++c) {
                float s = conf * sigf(p[(5 + c) * HW]);
                // sub-threshold scores are -1.0 sentinels in the reference: inert in
                // NMS and emitted as pad rows -> interchangeable with our pads, skip.
                if (s < 0.01f) continue;
                u32 m = mono32(s);
                if (MODE == 0) {
                    atomicAdd(&h[(m >> 21) * 4 + (tid & 3)], 1u);
                } else if (MODE == 1) {
                    if ((m >> 21) == b1) atomicAdd(&h[(m >> 9) & 0xFFFu], 1u);
                } else {
                    if ((m >> 9) >= T) {
                        u32 pos = atomicAdd(&cnt[b], 1u);
                        if (pos < CAP) {
                            u32 e = (u32)(g * 80 + c);   // reference flat index
                            cand[b * CAP + pos] = ((u64)m << 32) | (u64)(0xFFFFFFFFu - e);
                        }
                    }
                }
            }
        }
    }
    if (MODE == 0) {
        __syncthreads();
        u32* gh = ghist + b * NBINS1;
        for (int i = tid; i < NBINS1; i += 256) {
            u32 s = h[i*4] + h[i*4+1] + h[i*4+2] + h[i*4+3];
            if (s) atomicAdd(&gh[i], s);
        }
    }
    if (MODE == 1) {
        __syncthreads();
        u32* gh = ghist + b * NBINS2;
        for (int i = tid; i < NBINS2; i += 256)
            if (h[i]) atomicAdd(&gh[i], h[i]);
    }
}

// Parallel pivot search over NB_ bins. LEVEL 1 (2048 bins): write sel1=(bin, cumAbove).
// LEVEL 2 (4096 bins, need = PRE - sel1.y): write clamped 23-bit prefix t23.
template<int LEVEL>
__global__ __launch_bounds__(256) void scan_k(const u32* __restrict__ ghist,
                                              int2* __restrict__ sel1,
                                              u32* __restrict__ t23)
{
    constexpr int NB_ = (LEVEL == 1) ? NBINS1 : NBINS2;
    constexpr int CH  = NB_ / 256;
    const int b = blockIdx.x;
    const int tid = threadIdx.x;
    const u32* h = ghist + b * NB_;
    __shared__ u32 lh[NB_];
    __shared__ u32 part[256];
    __shared__ u32 suf[256];

    const u32 need = (LEVEL == 1) ? (u32)PRE : (u32)(PRE - sel1[b].y);

    for (int i = tid; i < NB_; i += 256) lh[i] = h[i];
    if (tid == 0) {   // defaults for the degenerate (<need total) case
        if (LEVEL == 1) sel1[b] = make_int2(0, 0);
        else            t23[b]  = MIN_VALID_P9;     // gather all valid
    }
    __syncthreads();

    u32 ps = 0;
    #pragma unroll
    for (int i = 0; i < CH; ++i) ps += lh[tid * CH + i];
    part[tid] = ps;
    __syncthreads();

    if (tid == 0) {
        u32 cum = 0;
        for (int t = 255; t >= 0; --t) { suf[t] = cum; cum += part[t]; }
    }
    __syncthreads();

    if (suf[tid] < need && suf[tid] + part[tid] >= need) {   // exactly one thread
        u32 cum = suf[tid];
        for (int bin = tid * CH + CH - 1; bin >= tid * CH; --bin) {
            u32 c = lh[bin];
            if (cum + c >= need) {
                if (LEVEL == 1) {
                    sel1[b] = make_int2(bin, (int)cum);
                } else {
                    u32 t = ((u32)sel1[b].x << 12) | (u32)bin;
                    t23[b] = (t > MIN_VALID_P9) ? t : MIN_VALID_P9;
                }
                break;
            }
            cum += c;
        }
    }
}

// Rank-sort candidates (exact (val desc, idx asc) order) + decode top-400 boxes.
__global__ __launch_bounds__(512) void sortdec_k(
    const float* __restrict__ f0, const float* __restrict__ f1, const float* __restrict__ f2,
    const u32* __restrict__ cnt, const u64* __restrict__ cand,
    float4* __restrict__ DB, float* __restrict__ VALG, int* __restrict__ CLSG,
    u64* __restrict__ VBMG)
{
    __shared__ u64 keys[CAP];
    __shared__ u64 SKEY[PRE];
    const int b = blockIdx.x;
    const int tid = threadIdx.x;
    const int n = (int)min(cnt[b], (u32)CAP);

    for (int i = tid; i < n; i += 512) keys[i] = cand[b * CAP + i];
    for (int i = tid; i < PRE; i += 512) SKEY[i] = 0ull;
    __syncthreads();

    // rank sort: keys unique; broadcast LDS reads, 4x unrolled
    for (int e = tid; e < n; e += 512) {
        u64 my = keys[e];
        int r = 0, k = 0;
        for (; k + 4 <= n; k += 4)
            r += (int)(keys[k] > my) + (int)(keys[k+1] > my)
               + (int)(keys[k+2] > my) + (int)(keys[k+3] > my);
        for (; k < n; ++k) r += (int)(keys[k] > my);
        if (r < PRE) SKEY[r] = my;
    }
    __syncthreads();

    const int i = tid;
    bool valid = false;
    if (i < PRE) {
        u64 kk = SKEY[i];
        float v; int g, c;
        if (kk) {
            u32 m = (u32)(kk >> 32);
            u32 e = 0xFFFFFFFFu - (u32)(kk & 0xFFFFFFFFu);
            v = unmono(m); g = (int)(e / 80u); c = (int)(e - (u32)g * 80u);
            valid = true;                       // gathered scores all >= 0.01
        } else { v = -1.0f; g = 0; c = 0; }
        int HW, cw, ch; float stride, aw, ah;
        const float* p = box_base(f0, f1, f2, b, g, &HW, &cw, &ch, &stride, &aw, &ah);
        float cx = (sigf(p[0])  + (float)cw) * stride;
        float cy = (sigf(p[HW]) + (float)ch) * stride;
        float bw = expf(p[2 * HW]) * aw;
        float bh = expf(p[3 * HW]) * ah;
        DB[b * PRE + i] = make_float4(cx - bw * 0.5f, cy - bh * 0.5f,
                                      cx + bw * 0.5f, cy + bh * 0.5f);
        VALG[b * PRE + i] = v;
        CLSG[b * PRE + i] = c;
    }
    u64 bal = __ballot(valid);
    if ((tid & 63) == 0 && (tid >> 6) < 7) VBMG[b * 8 + (tid >> 6)] = bal;
}

// Suppression matrix, one block per (word w, batch b): SUPG[b][i][w] bit (j-64w)
// = box i suppresses box j (j>i, same class, IOU>0.45). All lanes share j ->
// LDS broadcast reads, conflict-free.
__global__ __launch_bounds__(256) void sup_k(const float4* __restrict__ DB,
                                             const int* __restrict__ CLSG,
                                             u64* __restrict__ SUPG)
{
    __shared__ float4 BX[PRE];
    __shared__ int LC[PRE];
    const int w = blockIdx.x, b = blockIdx.y;
    const int tid = threadIdx.x;
    for (int i = tid; i < PRE; i += 256) { BX[i] = DB[b * PRE + i]; LC[i] = CLSG[b * PRE + i]; }
    __syncthreads();

    const int jbase = w << 6;
    const int j1 = (jbase + 64 < PRE) ? (jbase + 64) : PRE;
    for (int i = tid; i < PRE; i += 256) {
        u64 mask = 0ull;
        if (w >= (i >> 6)) {
            float4 bi = BX[i]; int ci = LC[i];
            float ai = fmaxf(bi.z - bi.x, 0.f) * fmaxf(bi.w - bi.y, 0.f);
            for (int j = jbase; j < j1; ++j) {
                float4 bj = BX[j];
                bool ok = (LC[j] == ci) && (j > i);
                float ix1 = fmaxf(bi.x, bj.x), iy1 = fmaxf(bi.y, bj.y);
                float ix2 = fminf(bi.z, bj.z), iy2 = fminf(bi.w, bj.w);
                float inter = fmaxf(ix2 - ix1, 0.f) * fmaxf(iy2 - iy1, 0.f);
                float aj = fmaxf(bj.z - bj.x, 0.f) * fmaxf(bj.w - bj.y, 0.f);
                float iou = inter / fmaxf(ai + aj - inter, 1e-9f);
                if (ok && iou > 0.45f) mask |= 1ull << (j - jbase);
            }
        }
        SUPG[(b * PRE + i) * 7 + w] = mask;
    }
}

// Greedy NMS over bitmasks + rank-select top-200 + output.
__global__ __launch_bounds__(256) void nms_out_k(
    const u64* __restrict__ SUPG, const u64* __restrict__ VBMG,
    const float4* __restrict__ DB, const float* __restrict__ VALG,
    const int* __restrict__ CLSG, float* __restrict__ out)
{
    __shared__ u64 SUP[PRE][7];
    __shared__ float4 BX[PRE];
    __shared__ float VALs[PRE];
    __shared__ int LC[PRE];
    __shared__ u64 VBM[8];
    __shared__ u64 KBM[8];

    const int b = blockIdx.x;
    const int tid = threadIdx.x;

    for (int t = tid; t < PRE * 7; t += 256) ((u64*)SUP)[t] = SUPG[b * PRE * 7 + t];
    for (int i = tid; i < PRE; i += 256) {
        BX[i] = DB[b * PRE + i]; VALs[i] = VALG[b * PRE + i]; LC[i] = CLSG[b * PRE + i];
    }
    if (tid < 8) { VBM[tid] = (tid < 7) ? VBMG[b * 8 + tid] : 0ull; KBM[tid] = 0ull; }
    __syncthreads();

    // serial greedy over register bitmasks, 2-deep A/B row prefetch (rows contiguous)
    if (tid == 0) {
        u64 kp[7], A[7], B[7];
        #pragma unroll
        for (int w = 0; w < 7; ++w) kp[w] = VBM[w];
        #pragma unroll
        for (int w = 0; w < 7; ++w) A[w] = SUP[0][w];
        #pragma unroll
        for (int w = 0; w < 7; ++w) B[w] = SUP[1][w];
        #pragma unroll
        for (int w = 0; w < 7; ++w) {
            const int base = w << 6;
            const int lim = (w == 6) ? 16 : 64;   // PRE = 400
            for (int bi = 0; bi < lim; bi += 2) {
                int i = base + bi;
                if ((kp[w] >> bi) & 1) {
                    #pragma unroll
                    for (int w2 = 0; w2 < 7; ++w2) kp[w2] &= ~A[w2];
                }
                int ip2 = (i + 2 < PRE) ? (i + 2) : (PRE - 1);
                #pragma unroll
                for (int w2 = 0; w2 < 7; ++w2) A[w2] = SUP[ip2][w2];
                if ((kp[w] >> (bi + 1)) & 1) {
                    #pragma unroll
                    for (int w2 = 0; w2 < 7; ++w2) kp[w2] &= ~B[w2];
                }
                int ip3 = (i + 3 < PRE) ? (i + 3) : (PRE - 1);
                #pragma unroll
                for (int w2 = 0; w2 < 7; ++w2) B[w2] = SUP[ip3][w2];
            }
        }
        #pragma unroll
        for (int w = 0; w < 7; ++w) KBM[w] = kp[w];
    }
    __syncthreads();

    // rank-select top-200 (kept in order, then pads) and write output
    int totk = 0;
    #pragma unroll
    for (int w = 0; w < 7; ++w) totk += __popcll(KBM[w]);
    for (int j = tid; j < PRE; j += 256) {
        int w = j >> 6, bi = j & 63;
        int pre_kept = 0;
        for (int ww = 0; ww < w; ++ww) pre_kept += __popcll(KBM[ww]);
        u64 kw = KBM[w];
        pre_kept += __popcll(kw & ((1ull << bi) - 1ull));
        bool kept = (kw >> bi) & 1;
        int slot = kept ? pre_kept : (totk + j - pre_kept);
        if (slot < TOPK_N) {
            float* o = out + ((size_t)b * TOPK_N + slot) * 6;
            if (kept) {
                float4 bx = BX[j];
                o[0] = bx.x; o[1] = bx.y; o[2] = bx.z; o[3] = bx.w;
                o[4] = VALs[j]; o[5] = (float)LC[j];
            } else {
                o[0] = 0.f; o[1] = 0.f; o[2] = 0.f; o[3] = 0.f; o[4] = 0.f; o[5] = -1.f;
            }
        }
    }
}

extern "C" void kernel_launch(void* const* d_in, const int* in_sizes, int n_in,
                              void* d_out, int out_size, void* d_ws, size_t ws_size,
                              hipStream_t stream)
{
    const float* f0 = (const float*)d_in[0];
    const float* f1 = (const float*)d_in[1];
    const float* f2 = (const float*)d_in[2];
    float* out = (float*)d_out;
    char* ws = (char*)d_ws;

    // ws layout (~584 KB total)
    u32*    ghist1 = (u32*)(ws);                 //      0: 8*2048*4 = 65536
    u32*    ghist2 = (u32*)(ws + 65536);         //  65536: 8*4096*4 = 131072
    u32*    cnt    = (u32*)(ws + 196608);        // 196608: 32
    int2*   sel1   = (int2*)(ws + 196640);       // 196640: 64
    u32*    t23    = (u32*)(ws + 196704);        // 196704: 32
    u64*    VBMG   = (u64*)(ws + 196736);        // 196736: 8*8*8 = 512
    u64*    cand   = (u64*)(ws + 197248);        // 197248: 8*2048*8 = 131072
    float4* DB     = (float4*)(ws + 328320);     // 328320: 8*400*16 = 51200
    float*  VALG   = (float*)(ws + 379520);      // 379520: 8*400*4 = 12800
    int*    CLSG   = (int*)(ws + 392320);        // 392320: 12800
    u64*    SUPG   = (u64*)(ws + 405120);        // 405120: 8*400*7*8 = 179200 -> 584320

    hipMemsetAsync(ws, 0, 196640, stream);       // zero ghist1, ghist2, cnt

    dim3 grid((NB + 255) / 256, NBATCH);
    score_pass<0><<<grid, 256, 0, stream>>>(f0, f1, f2, ghist1, sel1, t23, cnt, cand);
    scan_k<1><<<NBATCH, 256, 0, stream>>>(ghist1, sel1, t23);
    score_pass<1><<<grid, 256, 0, stream>>>(f0, f1, f2, ghist2, sel1, t23, cnt, cand);
    scan_k<2><<<NBATCH, 256, 0, stream>>>(ghist2, sel1, t23);
    score_pass<2><<<grid, 256, 0, stream>>>(f0, f1, f2, ghist1, sel1, t23, cnt, cand);
    sortdec_k<<<NBATCH, 512, 0, stream>>>(f0, f1, f2, cnt, cand, DB, VALG, CLSG, VBMG);
    sup_k<<<dim3(7, NBATCH), 256, 0, stream>>>(DB, CLSG, SUPG);
    nms_out_k<<<NBATCH, 256, 0, stream>>>(SUPG, VBMG, DB, VALG, CLSG, out);
}